// Round 1
// baseline (14294.052 us; speedup 1.0000x reference)
//
#include <hip/hip_runtime.h>

#define B_ 64
#define T_ 512
#define D_ 1024
#define H_ 1024

typedef _Float16 half8 __attribute__((ext_vector_type(8)));
typedef float floatx16 __attribute__((ext_vector_type(16)));

__device__ __forceinline__ float sigm(float x)   { return 1.f / (1.f + __expf(-x)); }
__device__ __forceinline__ float tanh_f(float x) { return 1.f - 2.f / (1.f + __expf(2.f * x)); }

// ---------------- prep: inputs fp32 -> f16 (8 elems / thread) ----------------
__global__ void k_prep_x(const float* __restrict__ x, _Float16* __restrict__ xf) {
  int i = blockIdx.x * blockDim.x + threadIdx.x;   // 0 .. 4194303
  const float4* p = (const float4*)x + (size_t)i * 2;
  float4 a = p[0], b = p[1];
  half8 v;
  v[0]=(_Float16)a.x; v[1]=(_Float16)a.y; v[2]=(_Float16)a.z; v[3]=(_Float16)a.w;
  v[4]=(_Float16)b.x; v[5]=(_Float16)b.y; v[6]=(_Float16)b.z; v[7]=(_Float16)b.w;
  ((half8*)xf)[i] = v;
}

// ---------------- prep: h_{-1} = init_h (f16), zero flags ----------------
__global__ void k_prep_misc(const float* __restrict__ init_h,
                            _Float16* __restrict__ hb1, int* __restrict__ flags) {
  int i = blockIdx.x * blockDim.x + threadIdx.x;   // grid 256x256 = 65536
  hb1[i] = (_Float16)init_h[i];
  if (i < 4096) flags[i] = 0;
}

// ---------------- persistent LSTM kernel ----------------
// 256 WGs (1/CU), 256 threads (4 waves). WG w: batch-half bh=w>>7, col-chunk jc=w&127
// (8 hidden cols -> 32 z-cols {gate*H + jc*8+jj}). LDS slab holds [Wi;Wh] slice,
// K=2048, in MFMA B-frag order: slab[kb*512 + lane*8 + j], kb=k/16.
template <bool XF16>
__launch_bounds__(256, 1)
__global__ void k_lstm(const float* __restrict__ x32, const _Float16* __restrict__ xf,
                       const int* __restrict__ lengths, const float* __restrict__ init_c,
                       const float* __restrict__ Wi, const float* __restrict__ Wh,
                       const float* __restrict__ bias,
                       _Float16* __restrict__ hb0, _Float16* __restrict__ hb1,
                       int* __restrict__ flags,
                       float* __restrict__ out, float* __restrict__ finc,
                       float* __restrict__ finh)
{
  __shared__ _Float16 slab[65536];   // 128 KB: 128 kb-blocks x 512 f16
  __shared__ float red[4][32][40];   // 20 KB: wave partials, stride 40 = conflict-free

  const int w    = blockIdx.x;
  const int bh   = w >> 7;
  const int jc   = w & 127;
  const int t    = threadIdx.x;
  const int wave = t >> 6;
  const int lane = t & 63;
  const int m    = lane & 31;
  const int kh   = lane >> 5;

  // ---- one-time gather: weights -> LDS slab (f16, fragment order) ----
  {
    const int gate = m >> 3;
    const int col  = gate * H_ + jc * 8 + (m & 7);
    for (int kbb = 0; kbb < 32; ++kbb) {
      const int kb = kbb * 4 + wave;
      const int kc = kb * 16 + kh * 8;
      half8 v;
      #pragma unroll
      for (int j = 0; j < 8; ++j) {
        const int k = kc + j;
        const float f = (k < D_) ? Wi[(size_t)k * 4096 + col]
                                 : Wh[(size_t)(k - D_) * 4096 + col];
        v[j] = (_Float16)f;
      }
      *(half8*)&slab[kb * 512 + lane * 8] = v;
    }
  }

  // ---- per-thread gate-phase ids: one (batch, hidden-col) pair ----
  const int bl = t >> 3, jj = t & 7;
  const int bG = bh * 32 + bl;
  const int jG = jc * 8 + jj;
  float c = init_c[bG * H_ + jG];
  const int len = lengths[bG];
  const float bz0 = bias[0 * H_ + jG];
  const float bz1 = bias[1 * H_ + jG];
  const float bz2 = bias[2 * H_ + jG];
  const float bz3 = bias[3 * H_ + jG];

  const int bA = bh * 32 + m;                         // A-fragment row (batch)
  const _Float16* xbase  = XF16 ? (xf + (size_t)bA * T_ * D_ + kh * 8) : (const _Float16*)0;
  const float*    xbase32 = x32 + (size_t)bA * T_ * D_ + kh * 8;

  int* myflag_w = flags + (w << 4);    // flags padded to 64 B
  int* myflag_p = flags + (t << 4);    // thread t polls WG t's flag

  __syncthreads();

  for (int s = 0; s < T_; ++s) {
    floatx16 C;
    #pragma unroll
    for (int r = 0; r < 16; ++r) C[r] = 0.f;

    // ---- x phase (independent of h; hides sync latency) ----
    half8 a[16];
    if (XF16) {
      const _Float16* xs = xbase + (size_t)s * D_;
      #pragma unroll
      for (int i = 0; i < 16; ++i)
        a[i] = *(const half8*)(xs + (wave * 16 + i) * 16);
    } else {
      const float* xs = xbase32 + (size_t)s * D_;
      #pragma unroll
      for (int i = 0; i < 16; ++i) {
        const float4* p = (const float4*)(xs + (wave * 16 + i) * 16);
        float4 u0 = p[0], u1 = p[1];
        half8 v;
        v[0]=(_Float16)u0.x; v[1]=(_Float16)u0.y; v[2]=(_Float16)u0.z; v[3]=(_Float16)u0.w;
        v[4]=(_Float16)u1.x; v[5]=(_Float16)u1.y; v[6]=(_Float16)u1.z; v[7]=(_Float16)u1.w;
        a[i] = v;
      }
    }
    #pragma unroll
    for (int i = 0; i < 16; ++i) {
      const half8 bf = *(const half8*)&slab[(wave * 16 + i) * 512 + lane * 8];
      C = __builtin_amdgcn_mfma_f32_32x32x16_f16(a[i], bf, C, 0, 0, 0);
    }

    // ---- wait for h_{s-1}: distributed flag poll (no fence; h read bypasses caches) ----
    {
      int spin = 0;
      while (__hip_atomic_load(myflag_p, __ATOMIC_RELAXED, __HIP_MEMORY_SCOPE_AGENT) < s) {
        __builtin_amdgcn_s_sleep(2);
        if (++spin > (1 << 22)) break;   // safety valve against deadlock-hang
      }
    }
    __syncthreads();

    // ---- h phase: A-frags via agent-scope loads (sc0/sc1 -> always fresh from LLC) ----
    const _Float16* hsrc = (s & 1) ? hb0 : hb1;   // (s-1)&1 == (s+1)&1
    unsigned long long* hp =
        (unsigned long long*)(hsrc + (size_t)bA * H_ + kh * 8);
    #pragma unroll
    for (int i = 0; i < 16; ++i) {
      const int k = (wave * 16 + i) * 16;
      unsigned long long q0 = __hip_atomic_load(hp + (k >> 2),     __ATOMIC_RELAXED, __HIP_MEMORY_SCOPE_AGENT);
      unsigned long long q1 = __hip_atomic_load(hp + (k >> 2) + 1, __ATOMIC_RELAXED, __HIP_MEMORY_SCOPE_AGENT);
      union { unsigned long long q[2]; half8 v; } u;
      u.q[0] = q0; u.q[1] = q1;
      const half8 bf = *(const half8*)&slab[(64 + wave * 16 + i) * 512 + lane * 8];
      C = __builtin_amdgcn_mfma_f32_32x32x16_f16(u.v, bf, C, 0, 0, 0);
    }

    // ---- reduce 4-wave partials (C/D layout: col=lane&31, row=(r&3)+8*(r>>2)+4*(lane>>5)) ----
    #pragma unroll
    for (int r = 0; r < 16; ++r) {
      const int row = (r & 3) + 8 * (r >> 2) + 4 * kh;
      red[wave][row][m] = C[r];
    }
    __syncthreads();

    const float z0 = red[0][bl][jj]      + red[1][bl][jj]      + red[2][bl][jj]      + red[3][bl][jj]      + bz0;
    const float z1 = red[0][bl][8 + jj]  + red[1][bl][8 + jj]  + red[2][bl][8 + jj]  + red[3][bl][8 + jj]  + bz1;
    const float z2 = red[0][bl][16 + jj] + red[1][bl][16 + jj] + red[2][bl][16 + jj] + red[3][bl][16 + jj] + bz2;
    const float z3 = red[0][bl][24 + jj] + red[1][bl][24 + jj] + red[2][bl][24 + jj] + red[3][bl][24 + jj] + bz3;

    const float ig = sigm(z0);
    const float fg = sigm(z1);
    const float gg = tanh_f(z2);
    const float og = sigm(z3);
    c = fg * c + ig * gg;
    const float hv = og * tanh_f(c);

    out[((size_t)bG * T_ + s) * H_ + jG] = hv;
    _Float16* hdst = (s & 1) ? hb1 : hb0;
    hdst[(size_t)bG * H_ + jG] = (_Float16)hv;
    if (s == len - 1) { finc[bG * H_ + jG] = c; finh[bG * H_ + jG] = hv; }

    __threadfence();      // drain own stores + L2 writeback -> LLC (cross-XCD visibility)
    __syncthreads();      // all threads' fences done before flag
    if (t == 0)
      __hip_atomic_store(myflag_w, s + 1, __ATOMIC_RELAXED, __HIP_MEMORY_SCOPE_AGENT);
  }
}

// ---------------- host ----------------
extern "C" void kernel_launch(void* const* d_in, const int* in_sizes, int n_in,
                              void* d_out, int out_size, void* d_ws, size_t ws_size,
                              hipStream_t stream) {
  const float* x32    = (const float*)d_in[0];
  const int*   lens   = (const int*)  d_in[1];
  const float* init_c = (const float*)d_in[2];
  const float* init_h = (const float*)d_in[3];
  const float* Wi     = (const float*)d_in[4];
  const float* Wh     = (const float*)d_in[5];
  const float* bias   = (const float*)d_in[6];

  float* out   = (float*)d_out;
  float* fin_c = out + (size_t)B_ * T_ * H_;
  float* fin_h = fin_c + (size_t)B_ * H_;

  char* ws = (char*)d_ws;
  int*       flags = (int*)ws;                         // 16 KB (256 flags, 64-B padded)
  _Float16*  hb0   = (_Float16*)(ws + 16384);          // 128 KB
  _Float16*  hb1   = hb0 + (size_t)B_ * H_;            // 128 KB
  _Float16*  xf16  = (_Float16*)(ws + (1u << 20));     // 64 MB

  const size_t need_big = (1u << 20) + sizeof(_Float16) * (size_t)B_ * T_ * D_;

  k_prep_misc<<<256, 256, 0, stream>>>(init_h, hb1, flags);
  if (ws_size >= need_big) {
    k_prep_x<<<16384, 256, 0, stream>>>(x32, xf16);
    k_lstm<true><<<256, 256, 0, stream>>>(x32, xf16, lens, init_c, Wi, Wh, bias,
                                          hb0, hb1, flags, out, fin_c, fin_h);
  } else {
    k_lstm<false><<<256, 256, 0, stream>>>(x32, xf16, lens, init_c, Wi, Wh, bias,
                                           hb0, hb1, flags, out, fin_c, fin_h);
  }
}

// Round 2
// 6419.537 us; speedup vs baseline: 2.2266x; 2.2266x over previous
//
#include <hip/hip_runtime.h>

#define B_ 64
#define T_ 512
#define D_ 1024
#define H_ 1024

typedef _Float16 half8 __attribute__((ext_vector_type(8)));
typedef float floatx16 __attribute__((ext_vector_type(16)));

__device__ __forceinline__ float sigm(float x)   { return 1.f / (1.f + __expf(-x)); }
__device__ __forceinline__ float tanh_f(float x) { return 1.f - 2.f / (1.f + __expf(2.f * x)); }

// ---------------- prep: inputs fp32 -> f16 (8 elems / thread) ----------------
__global__ void k_prep_x(const float* __restrict__ x, _Float16* __restrict__ xf) {
  int i = blockIdx.x * blockDim.x + threadIdx.x;   // 0 .. 4194303
  const float4* p = (const float4*)x + (size_t)i * 2;
  float4 a = p[0], b = p[1];
  half8 v;
  v[0]=(_Float16)a.x; v[1]=(_Float16)a.y; v[2]=(_Float16)a.z; v[3]=(_Float16)a.w;
  v[4]=(_Float16)b.x; v[5]=(_Float16)b.y; v[6]=(_Float16)b.z; v[7]=(_Float16)b.w;
  ((half8*)xf)[i] = v;
}

// ---------------- prep: h_{-1} = init_h (f16), zero flags ----------------
__global__ void k_prep_misc(const float* __restrict__ init_h,
                            _Float16* __restrict__ hb1, int* __restrict__ flags) {
  int i = blockIdx.x * blockDim.x + threadIdx.x;   // grid 256x256 = 65536
  hb1[i] = (_Float16)init_h[i];
  if (i < 4096) flags[i] = 0;
}

// ---------------- persistent LSTM kernel ----------------
// 256 WGs (1/CU), 256 threads (4 waves). WG w: batch-half bh=w>>7, col-chunk jc=w&127
// (8 hidden cols -> 32 z-cols {gate*H + jc*8+jj}). LDS slab holds [Wi;Wh] slice,
// K=2048, in MFMA B-frag order: slab[kb*512 + lane*8 + j], kb=k/16.
//
// Cross-WG h exchange protocol (no wbl2 anywhere):
//   writers: packed f16x2 relaxed AGENT atomic stores (sc0|sc1 write-through to LLC,
//            L2 stays clean) -> __syncthreads (drains vmcnt(0)) -> flag relaxed store.
//   readers: poll 128 same-bh flags (relaxed agent loads, bypass caches) ->
//            __syncthreads -> acquire fence (buffer_inv: cheap tag invalidate) ->
//            PLAIN vectorized half8 loads (L2-cached -> shared by 16 WGs/XCD).
template <bool XF16>
__launch_bounds__(256, 1)
__global__ void k_lstm(const float* __restrict__ x32, const _Float16* __restrict__ xf,
                       const int* __restrict__ lengths, const float* __restrict__ init_c,
                       const float* __restrict__ Wi, const float* __restrict__ Wh,
                       const float* __restrict__ bias,
                       _Float16* __restrict__ hb0, _Float16* __restrict__ hb1,
                       int* __restrict__ flags,
                       float* __restrict__ out, float* __restrict__ finc,
                       float* __restrict__ finh)
{
  __shared__ _Float16 slab[65536];   // 128 KB: 128 kb-blocks x 512 f16
  __shared__ float red[4][32][40];   // 20 KB: wave partials, stride 40 = conflict-free

  const int w    = blockIdx.x;
  const int bh   = w >> 7;
  const int jc   = w & 127;
  const int t    = threadIdx.x;
  const int wave = t >> 6;
  const int lane = t & 63;
  const int m    = lane & 31;
  const int kh   = lane >> 5;

  // ---- one-time gather: weights -> LDS slab (f16, fragment order) ----
  {
    const int gate = m >> 3;
    const int col  = gate * H_ + jc * 8 + (m & 7);
    for (int kbb = 0; kbb < 32; ++kbb) {
      const int kb = kbb * 4 + wave;
      const int kc = kb * 16 + kh * 8;
      half8 v;
      #pragma unroll
      for (int j = 0; j < 8; ++j) {
        const int k = kc + j;
        const float f = (k < D_) ? Wi[(size_t)k * 4096 + col]
                                 : Wh[(size_t)(k - D_) * 4096 + col];
        v[j] = (_Float16)f;
      }
      *(half8*)&slab[kb * 512 + lane * 8] = v;
    }
  }

  // ---- per-thread gate-phase ids: one (batch, hidden-col) pair ----
  const int bl = t >> 3, jj = t & 7;
  const int bG = bh * 32 + bl;
  const int jG = jc * 8 + jj;
  float c = init_c[bG * H_ + jG];
  const int len = lengths[bG];
  const float bz0 = bias[0 * H_ + jG];
  const float bz1 = bias[1 * H_ + jG];
  const float bz2 = bias[2 * H_ + jG];
  const float bz3 = bias[3 * H_ + jG];

  const int bA = bh * 32 + m;                         // A-fragment row (batch)
  const _Float16* xbase  = XF16 ? (xf + (size_t)bA * T_ * D_ + kh * 8) : (const _Float16*)0;
  const float*    xbase32 = x32 + (size_t)bA * T_ * D_ + kh * 8;

  int* myflag_w = flags + (w << 4);                        // flags padded to 64 B
  int* myflag_p = flags + ((bh * 128 + (t & 127)) << 4);   // threads 0..127 poll same-bh producers

  __syncthreads();

  for (int s = 0; s < T_; ++s) {
    floatx16 C;
    #pragma unroll
    for (int r = 0; r < 16; ++r) C[r] = 0.f;

    // ---- x phase (independent of h; hides sync latency) ----
    half8 a[16];
    if (XF16) {
      const _Float16* xs = xbase + (size_t)s * D_;
      #pragma unroll
      for (int i = 0; i < 16; ++i)
        a[i] = *(const half8*)(xs + (wave * 16 + i) * 16);
    } else {
      const float* xs = xbase32 + (size_t)s * D_;
      #pragma unroll
      for (int i = 0; i < 16; ++i) {
        const float4* p = (const float4*)(xs + (wave * 16 + i) * 16);
        float4 u0 = p[0], u1 = p[1];
        half8 v;
        v[0]=(_Float16)u0.x; v[1]=(_Float16)u0.y; v[2]=(_Float16)u0.z; v[3]=(_Float16)u0.w;
        v[4]=(_Float16)u1.x; v[5]=(_Float16)u1.y; v[6]=(_Float16)u1.z; v[7]=(_Float16)u1.w;
        a[i] = v;
      }
    }
    #pragma unroll
    for (int i = 0; i < 16; ++i) {
      const half8 bf = *(const half8*)&slab[(wave * 16 + i) * 512 + lane * 8];
      C = __builtin_amdgcn_mfma_f32_32x32x16_f16(a[i], bf, C, 0, 0, 0);
    }

    // ---- wait for h_{s-1}: threads 0..127 poll the 128 same-bh producer flags ----
    if (t < 128) {
      int spin = 0;
      while (__hip_atomic_load(myflag_p, __ATOMIC_RELAXED, __HIP_MEMORY_SCOPE_AGENT) < s) {
        __builtin_amdgcn_s_sleep(1);
        if (++spin > (1 << 22)) break;   // safety valve against deadlock-hang
      }
    }
    __syncthreads();
    // acquire: buffer_inv (tag invalidate of L1/L2 stale lines) -- NOT a writeback
    __builtin_amdgcn_fence(__ATOMIC_ACQUIRE, "agent");

    // ---- h phase: plain vectorized loads (L2-cacheable, shared across WGs in XCD) ----
    const _Float16* hsrc = (s & 1) ? hb0 : hb1;   // h_{s-1} buffer
    const _Float16* hrow = hsrc + (size_t)bA * H_ + kh * 8;
    #pragma unroll
    for (int i = 0; i < 16; ++i) {
      const half8 av = *(const half8*)(hrow + (wave * 16 + i) * 16);
      const half8 bf = *(const half8*)&slab[(64 + wave * 16 + i) * 512 + lane * 8];
      C = __builtin_amdgcn_mfma_f32_32x32x16_f16(av, bf, C, 0, 0, 0);
    }

    // ---- reduce 4-wave partials (C/D layout: col=lane&31, row=(r&3)+8*(r>>2)+4*(lane>>5)) ----
    #pragma unroll
    for (int r = 0; r < 16; ++r) {
      const int row = (r & 3) + 8 * (r >> 2) + 4 * kh;
      red[wave][row][m] = C[r];
    }
    __syncthreads();

    const float z0 = red[0][bl][jj]      + red[1][bl][jj]      + red[2][bl][jj]      + red[3][bl][jj]      + bz0;
    const float z1 = red[0][bl][8 + jj]  + red[1][bl][8 + jj]  + red[2][bl][8 + jj]  + red[3][bl][8 + jj]  + bz1;
    const float z2 = red[0][bl][16 + jj] + red[1][bl][16 + jj] + red[2][bl][16 + jj] + red[3][bl][16 + jj] + bz2;
    const float z3 = red[0][bl][24 + jj] + red[1][bl][24 + jj] + red[2][bl][24 + jj] + red[3][bl][24 + jj] + bz3;

    const float ig = sigm(z0);
    const float fg = sigm(z1);
    const float gg = tanh_f(z2);
    const float og = sigm(z3);
    c = fg * c + ig * gg;
    const float hv = og * tanh_f(c);

    // ---- publish h_s FIRST (write-through to LLC, packed f16x2) ----
    {
      const float hv_other = __shfl_xor(hv, 1);   // partner lane jj^1 (same wave)
      if (!(t & 1)) {
        union { _Float16 h2[2]; unsigned u; } pk;
        pk.h2[0] = (_Float16)hv;
        pk.h2[1] = (_Float16)hv_other;
        _Float16* hdst = (s & 1) ? hb1 : hb0;
        __hip_atomic_store((unsigned*)(hdst + (size_t)bG * H_ + jG), pk.u,
                           __ATOMIC_RELAXED, __HIP_MEMORY_SCOPE_AGENT);
      }
    }

    out[((size_t)bG * T_ + s) * H_ + jG] = hv;
    if (s == len - 1) { finc[bG * H_ + jG] = c; finh[bG * H_ + jG] = hv; }

    // __syncthreads drains vmcnt(0) for every thread's stores (incl. the
    // write-through h stores, LLC-acked) before thread 0 publishes the flag.
    __syncthreads();
    if (t == 0)
      __hip_atomic_store(myflag_w, s + 1, __ATOMIC_RELAXED, __HIP_MEMORY_SCOPE_AGENT);
  }
}

// ---------------- host ----------------
extern "C" void kernel_launch(void* const* d_in, const int* in_sizes, int n_in,
                              void* d_out, int out_size, void* d_ws, size_t ws_size,
                              hipStream_t stream) {
  const float* x32    = (const float*)d_in[0];
  const int*   lens   = (const int*)  d_in[1];
  const float* init_c = (const float*)d_in[2];
  const float* init_h = (const float*)d_in[3];
  const float* Wi     = (const float*)d_in[4];
  const float* Wh     = (const float*)d_in[5];
  const float* bias   = (const float*)d_in[6];

  float* out   = (float*)d_out;
  float* fin_c = out + (size_t)B_ * T_ * H_;
  float* fin_h = fin_c + (size_t)B_ * H_;

  char* ws = (char*)d_ws;
  int*       flags = (int*)ws;                         // 16 KB (256 flags, 64-B padded)
  _Float16*  hb0   = (_Float16*)(ws + 16384);          // 128 KB
  _Float16*  hb1   = hb0 + (size_t)B_ * H_;            // 128 KB
  _Float16*  xf16  = (_Float16*)(ws + (1u << 20));     // 64 MB

  const size_t need_big = (1u << 20) + sizeof(_Float16) * (size_t)B_ * T_ * D_;

  k_prep_misc<<<256, 256, 0, stream>>>(init_h, hb1, flags);
  if (ws_size >= need_big) {
    k_prep_x<<<16384, 256, 0, stream>>>(x32, xf16);
    k_lstm<true><<<256, 256, 0, stream>>>(x32, xf16, lens, init_c, Wi, Wh, bias,
                                          hb0, hb1, flags, out, fin_c, fin_h);
  } else {
    k_lstm<false><<<256, 256, 0, stream>>>(x32, xf16, lens, init_c, Wi, Wh, bias,
                                           hb0, hb1, flags, out, fin_c, fin_h);
  }
}